// Round 4
// baseline (22.010 us; speedup 1.0000x reference)
//
#include <hip/hip_runtime.h>

// ---------------------------------------------------------------------------
// The 9-state/3-control LQR decouples per axis into a 3-state (p,v,a | jerk)
// chain; axes 0,1 share weights (type 0), axis 2 = yaw (type 1). The entire
// backward+forward pipeline is LINEAR in (targets, x0) with input-independent
// operators:
//   plan[b,t,a] = sum_s H_ty[t][s] * tgt[b,s,a] + sum_j G_ty[t][j] * x0[j][b,a]
// H (80x80) and G (80x3) per type are computed AT COMPILE TIME in double
// precision (constexpr), one object per type to stay under the constexpr
// step limit. Device work = one dense broadcast-GEMM kernel.
// ---------------------------------------------------------------------------

struct BasisT {
    float HT[80][80];   // HT[s][t]
    float GT[3][80];    // GT[j][t]
};

template <int TY>
constexpr BasisT build_basis() {
    BasisT B{};
    const double dt = 0.1, dt2 = 0.01, dt3 = 0.001;
    const double cxp = TY ? 10.0 : 1.0;    // YAW_W vs 1
    const double cxv = TY ? 1.0 : 0.0;     // YAW_VEL_W vs 0
    const double w   = TY ? 10.0 : 1.0;    // target scaling (tgt *= YAW_W on yaw)

    // ---- Riccati table (batch/input independent) ----
    double qx0[81] = {}, qx1[81] = {}, qx2[81] = {}, mm[81] = {};
    double kg0[81] = {}, kg1[81] = {}, kg2[81] = {};
    {
        double v00=0, v01=0, v02=0, v11=0, v12=0, v22=0;
        for (int t = 80; t >= 0; --t) {
            const double on = (t >= 1) ? 1.0 : 0.0;
            double Vb0 = v00*dt3 + v01*dt2 + v02*dt;
            double Vb1 = v01*dt3 + v11*dt2 + v12*dt;
            double Vb2 = v02*dt3 + v12*dt2 + v22*dt;
            double Quu = on*0.1 + dt3*Vb0 + dt2*Vb1 + dt*Vb2;
            double Qxu0 = Vb0;
            double Qxu1 = dt*Vb0 + Vb1;
            double Qxu2 = dt2*Vb0 + dt*Vb1 + Vb2;
            double M01 = dt*v00 + v01;
            double M02 = dt2*v00 + dt*v01 + v02;
            double M11 = dt*v01 + v11;
            double M12 = dt2*v01 + dt*v11 + v12;
            double M22 = dt2*v02 + dt*v12 + v22;
            double Q00 = on*cxp + v00;
            double Q11 = on*cxv + dt*M01 + M11;
            double Q12 = dt*M02 + M12;
            double Q22 = on*1.0 + dt2*M02 + dt*M12 + M22;
            double m = -1.0 / Quu;
            qx0[t] = Qxu0; qx1[t] = Qxu1; qx2[t] = Qxu2; mm[t] = m;
            kg0[t] = Qxu0*m; kg1[t] = Qxu1*m; kg2[t] = Qxu2*m;
            v00 = Q00 + m*Qxu0*Qxu0;
            v01 = M01 + m*Qxu0*Qxu1;
            v02 = M02 + m*Qxu0*Qxu2;
            v11 = Q11 + m*Qxu1*Qxu1;
            v12 = Q12 + m*Qxu1*Qxu2;
            v22 = Q22 + m*Qxu2*Qxu2;
        }
    }

    // ---- target impulse columns: H ----
    for (int sc = 0; sc < 80; ++sc) {
        double karr[80] = {};
        double v0 = 0, v1 = 0, v2 = 0;
        for (int t = sc + 1; t >= 1; --t) {     // v == 0 for t > sc+1
            double c  = (t - 1 == sc) ? -w : 0.0;
            double a1 = dt*v0 + v1;
            double a2 = dt*a1 + v2;
            double k  = dt*a2*mm[t];
            if (t <= 79) karr[t] = k;
            v0 = (c + v0) + qx0[t]*k;
            v1 = a1 + qx1[t]*k;
            v2 = a2 + qx2[t]*k;
        }
        {
            double a1 = dt*v0 + v1;
            double a2 = dt*a1 + v2;
            karr[0] = dt*a2*mm[0];
        }
        double p = 0, ve = 0, ac = 0;
        for (int t = 0; t < 80; ++t) {
            double u  = kg0[t]*p + kg1[t]*ve + kg2[t]*ac + karr[t];
            double pn = p + dt*ve + dt2*ac + dt3*u;
            double vn = ve + dt*ac + dt2*u;
            ac = ac + dt*u;
            p = pn; ve = vn;
            B.HT[sc][t] = (float)p;             // plan_t = position of x_{t+1}
        }
    }

    // ---- x0 columns: G (no target -> k == 0) ----
    for (int j = 0; j < 3; ++j) {
        double p = (j == 0), ve = (j == 1), ac = (j == 2);
        for (int t = 0; t < 80; ++t) {
            double u  = kg0[t]*p + kg1[t]*ve + kg2[t]*ac;
            double pn = p + dt*ve + dt2*ac + dt3*u;
            double vn = ve + dt*ac + dt2*u;
            ac = ac + dt*u;
            p = pn; ve = vn;
            B.GT[j][t] = (float)p;
        }
    }
    return B;
}

__device__ constexpr BasisT g_b0 = build_basis<0>();   // axes x, y
__device__ constexpr BasisT g_b1 = build_basis<1>();   // yaw

// ---------------------------------------------------------------------------
// Apply kernel. Grid 256 = 128 batch-groups x 2 t-halves; the two halves of a
// group are placed on the SAME XCD (bid%8) so the duplicated target fetch is
// an L2 hit. Block 256 = 4 waves; lane = batch (64/block); wave w handles the
// wave-uniform t-tile t0 = th*40 + w*10 for all 3 axes (10 acc each).
// Targets staged column-major sm[f*65 + batch]: stride 65 (odd) makes both
// the (q,m)-mapped staging writes and the compute reads 2-way (free) bank
// aliasing. H/G reads are wave-uniform -> scalar-pipe broadcast.
// ---------------------------------------------------------------------------
__global__ __launch_bounds__(256) void lqr_apply_kernel(
        const float* __restrict__ ego,   // (8192, 9)
        const float* __restrict__ ap,    // (8192, 6, 80, 3)
        float* __restrict__ out) {       // (8192, 80, 3)
    __shared__ float sm[15616];          // 240 x 65 (+pad) = 62464 B
    const int tid = threadIdx.x;
    const int bid = blockIdx.x;
    const int xcd = bid & 7;
    const int th  = (bid >> 3) & 1;
    const int bg  = ((bid >> 4) << 3) | xcd;   // 0..127
    const int b0  = bg * 64;
    const int w   = tid >> 6;
    const int l   = tid & 63;

    // ---- stage targets: 16-lane groups read 256B contiguous chunks ----
    {
        const int q = l >> 4, m = l & 15;
        #pragma unroll
        for (int p = 0; p < 4; ++p) {
            const int bb = p * 16 + w * 4 + q;
            const float* src = ap + (size_t)(b0 + bb) * 1440 + 1200;
            #pragma unroll
            for (int it = 0; it < 4; ++it) {
                const int c = m + 16 * it;
                if (c < 60) {
                    float4 v = *(const float4*)(src + 4 * c);
                    sm[(4*c + 0) * 65 + bb] = v.x;
                    sm[(4*c + 1) * 65 + bb] = v.y;
                    sm[(4*c + 2) * 65 + bb] = v.z;
                    sm[(4*c + 3) * 65 + bb] = v.w;
                }
            }
        }
    }
    __syncthreads();

    const int wid = __builtin_amdgcn_readfirstlane(w);
    const int t0  = th * 40 + wid * 10;
    const int b   = b0 + l;

    float x0[9];
    #pragma unroll
    for (int j = 0; j < 9; ++j) x0[j] = ego[b * 9 + j];

    float a0[10], a1[10], a2[10];
    #pragma unroll
    for (int i = 0; i < 10; ++i) {
        const int t = t0 + i;
        a0[i] = g_b0.GT[0][t]*x0[0] + g_b0.GT[1][t]*x0[3] + g_b0.GT[2][t]*x0[6];
        a1[i] = g_b0.GT[0][t]*x0[1] + g_b0.GT[1][t]*x0[4] + g_b0.GT[2][t]*x0[7];
        a2[i] = g_b1.GT[0][t]*x0[2] + g_b1.GT[1][t]*x0[5] + g_b1.GT[2][t]*x0[8];
    }

    #pragma unroll 2
    for (int s = 0; s < 80; ++s) {
        const float xv0 = sm[(3*s + 0) * 65 + l];
        const float xv1 = sm[(3*s + 1) * 65 + l];
        const float xv2 = sm[(3*s + 2) * 65 + l];
        const float* h0 = &g_b0.HT[s][t0];
        const float* h1 = &g_b1.HT[s][t0];
        #pragma unroll
        for (int i = 0; i < 10; ++i) {
            const float hv = h0[i];                 // shared by axes 0,1
            a0[i] = fmaf(hv,    xv0, a0[i]);
            a1[i] = fmaf(hv,    xv1, a1[i]);
            a2[i] = fmaf(h1[i], xv2, a2[i]);
        }
    }

    float* ob = out + (size_t)b * 240 + t0 * 3;     // 120B contiguous region
    #pragma unroll
    for (int i = 0; i < 10; ++i) {
        ob[i*3 + 0] = a0[i];
        ob[i*3 + 1] = a1[i];
        ob[i*3 + 2] = a2[i];
    }
}

extern "C" void kernel_launch(void* const* d_in, const int* in_sizes, int n_in,
                              void* d_out, int out_size, void* d_ws, size_t ws_size,
                              hipStream_t stream) {
    const float* ego = (const float*)d_in[0];   // (8192, 9)
    const float* ap  = (const float*)d_in[1];   // (8192, 6, 80, 3)
    float*       out = (float*)d_out;           // (8192, 80, 3)
    lqr_apply_kernel<<<256, 256, 0, stream>>>(ego, ap, out);
}